// Round 9
// baseline (248.214 us; speedup 1.0000x reference)
//
#include <hip/hip_runtime.h>

typedef unsigned short ushort_t;
typedef unsigned int uint_t;
typedef __bf16 bf16x8 __attribute__((ext_vector_type(8)));
typedef float f32x4 __attribute__((ext_vector_type(4)));
typedef uint_t u32x4 __attribute__((ext_vector_type(4)));
typedef uint_t u32x2 __attribute__((ext_vector_type(2)));

// B=16, C=512, T=1024, NH=8, D=64, groups=32 (16 ch/group)
// K is pre-scaled by 0.125*log2(e) at QKV time so attn softmax is exp2(raw).
// Sync discipline: __syncthreads ONLY, round-6 protocol everywhere.
// Round-8 verdict: 512-thread/QBLK-256 attn is deterministically broken -> retired.
// Single change vs round 6: k_attn launched as 1D grid with XCD-aware decode so
// the 8 qt-blocks sharing one (b,h)'s K/V land on ONE XCD (bid%8 = XCD, m09).

static __device__ __forceinline__ ushort_t f2bf(float f) {
  union { float f; uint_t u; } v; v.f = f;
  uint_t r = v.u + 0x7FFFu + ((v.u >> 16) & 1u);
  return (ushort_t)(r >> 16);
}

static __device__ __forceinline__ uint_t cvt_pk_bf16(float lo, float hi) {
  uint_t r;
  asm("v_cvt_pk_bf16_f32 %0, %1, %2" : "=v"(r) : "v"(lo), "v"(hi));
  return r;
}

static __device__ __forceinline__ f32x4 mfma_bf16(bf16x8 a, bf16x8 b, f32x4 c) {
  return __builtin_amdgcn_mfma_f32_16x16x32_bf16(a, b, c, 0, 0, 0);
}

// ---------------- fp32 -> bf16 convert ----------------
__global__ __launch_bounds__(256) void k_convert(const float* __restrict__ src,
                                                 ushort_t* __restrict__ dst, int n) {
  int i = (blockIdx.x * 256 + threadIdx.x) * 4;
  if (i >= n) return;
  f32x4 v = *(const f32x4*)(src + i);
  u32x2 o;
  o[0] = (uint_t)f2bf(v[0]) | ((uint_t)f2bf(v[1]) << 16);
  o[1] = (uint_t)f2bf(v[2]) | ((uint_t)f2bf(v[3]) << 16);
  *(u32x2*)(dst + i) = o;
}

// ---------------- GroupNorm + transpose -> xnT (b, t, c) bf16 (round-2 exact) ----
__global__ __launch_bounds__(256) void k_gn(const float* __restrict__ x,
                                            const float* __restrict__ gsc,
                                            const float* __restrict__ gbi,
                                            ushort_t* __restrict__ xnT) {
  const int g = blockIdx.x, b = blockIdx.y;
  const int tid = threadIdx.x;
  const float* xp = x + ((size_t)b * 512 + g * 16) * 1024;

  float s = 0.f, q = 0.f;
#pragma unroll
  for (int i = 0; i < 16; ++i) {
    f32x4 v = *(const f32x4*)(xp + (tid + i * 256) * 4);
    s += v[0] + v[1] + v[2] + v[3];
    q += v[0]*v[0] + v[1]*v[1] + v[2]*v[2] + v[3]*v[3];
  }
#pragma unroll
  for (int off = 32; off > 0; off >>= 1) { s += __shfl_xor(s, off); q += __shfl_xor(q, off); }

  __shared__ float rs[4], rq[4], ssc[16], sbi[16], stats[2];
  if ((tid & 63) == 0) { rs[tid >> 6] = s; rq[tid >> 6] = q; }
  if (tid < 16) { ssc[tid] = gsc[g * 16 + tid]; sbi[tid] = gbi[g * 16 + tid]; }
  __syncthreads();
  if (tid == 0) {
    float S = rs[0] + rs[1] + rs[2] + rs[3];
    float Q = rq[0] + rq[1] + rq[2] + rq[3];
    float mean = S * (1.f / 16384.f);
    float var  = Q * (1.f / 16384.f) - mean * mean;
    stats[0] = mean; stats[1] = rsqrtf(var + 1e-5f);
  }
  __syncthreads();
  const float mean = stats[0], rstd = stats[1];

#pragma unroll
  for (int i = 0; i < 8; ++i) {
    int u = tid + i * 256;          // 2048 units: (t, half)
    int t = u >> 1, half = u & 1;
    union { ushort_t us[8]; u32x4 v4; } o;
#pragma unroll
    for (int j = 0; j < 8; ++j) {
      int c = half * 8 + j;
      float v = (xp[(size_t)c * 1024 + t] - mean) * rstd * ssc[c] + sbi[c];
      o.us[j] = f2bf(v);
    }
    *(u32x4*)(xnT + ((size_t)b * 1024 + t) * 512 + g * 16 + half * 8) = o.v4;
  }
}

// ---------------- QKV GEMM (round-6 exact): D[t][o] = sum_c xnT[b][t][c]*W[o][c] ----
__global__ __launch_bounds__(256) void k_qkv(const ushort_t* __restrict__ xnT,
                                             const ushort_t* __restrict__ Wbf,
                                             const float* __restrict__ bias,
                                             ushort_t* __restrict__ qkT,
                                             ushort_t* __restrict__ vbuf) {
  const int mi = blockIdx.x, ni = blockIdx.y, b = blockIdx.z;
  const int tid = threadIdx.x, lane = tid & 63, w = tid >> 6;
  const int wm = w >> 1, wn = w & 1;
  const int lr = lane & 15, lg = lane >> 4;

  __shared__ __align__(16) ushort_t As[128 * 40];
  __shared__ __align__(16) ushort_t Bs[128 * 40];
  __shared__ __align__(16) float tbuf[32 * 132];

  const ushort_t* Ap = xnT + (size_t)b * 1024 * 512 + (size_t)mi * 128 * 512;
  const ushort_t* Bp = Wbf + (size_t)ni * 128 * 512;

  const int row0 = tid >> 2, seg = tid & 3;
  u32x4 ra0, ra1, rb0, rb1;

  // prologue: stage kt=0 (load + LDS write + barrier)
  ra0 = *(const u32x4*)(Ap + (size_t)row0 * 512 + seg * 8);
  ra1 = *(const u32x4*)(Ap + (size_t)(row0 + 64) * 512 + seg * 8);
  rb0 = *(const u32x4*)(Bp + (size_t)row0 * 512 + seg * 8);
  rb1 = *(const u32x4*)(Bp + (size_t)(row0 + 64) * 512 + seg * 8);
  *(u32x4*)(As + row0 * 40 + seg * 8) = ra0;
  *(u32x4*)(As + (row0 + 64) * 40 + seg * 8) = ra1;
  *(u32x4*)(Bs + row0 * 40 + seg * 8) = rb0;
  *(u32x4*)(Bs + (row0 + 64) * 40 + seg * 8) = rb1;
  __syncthreads();

  f32x4 acc[4][4] = {};

  for (int kt = 0; kt < 16; ++kt) {
    if (kt < 15) {                    // issue next-tile loads before compute
      const int k0n = (kt + 1) * 32;
      ra0 = *(const u32x4*)(Ap + (size_t)row0 * 512 + k0n + seg * 8);
      ra1 = *(const u32x4*)(Ap + (size_t)(row0 + 64) * 512 + k0n + seg * 8);
      rb0 = *(const u32x4*)(Bp + (size_t)row0 * 512 + k0n + seg * 8);
      rb1 = *(const u32x4*)(Bp + (size_t)(row0 + 64) * 512 + k0n + seg * 8);
    }
    bf16x8 af[4], bfv[4];
#pragma unroll
    for (int i = 0; i < 4; ++i)
      af[i] = *(const bf16x8*)(As + (wm * 64 + i * 16 + lr) * 40 + lg * 8);
#pragma unroll
    for (int j = 0; j < 4; ++j)
      bfv[j] = *(const bf16x8*)(Bs + (wn * 64 + j * 16 + lr) * 40 + lg * 8);
    __builtin_amdgcn_s_setprio(1);
#pragma unroll
    for (int i = 0; i < 4; ++i)
#pragma unroll
      for (int j = 0; j < 4; ++j)
        acc[i][j] = mfma_bf16(af[i], bfv[j], acc[i][j]);
    __builtin_amdgcn_s_setprio(0);
    if (kt < 15) {                    // block-uniform condition
      __syncthreads();                // all waves done reading As/Bs (full drain)
      *(u32x4*)(As + row0 * 40 + seg * 8) = ra0;
      *(u32x4*)(As + (row0 + 64) * 40 + seg * 8) = ra1;
      *(u32x4*)(Bs + row0 * 40 + seg * 8) = rb0;
      *(u32x4*)(Bs + (row0 + 64) * 40 + seg * 8) = rb1;
      __syncthreads();                // new tile visible
    }
  }

  float biasv[4];
#pragma unroll
  for (int j = 0; j < 4; ++j) biasv[j] = bias[ni * 128 + wn * 64 + j * 16 + lr];

  if (ni < 8) {
    // natural (t, o) write; K block (ni 4..7) pre-scaled for exp2 softmax
    const float oscale = (ni >= 4) ? 0.1803368801f : 1.0f;
    ushort_t* outp = qkT + ((size_t)b * 1024 + mi * 128) * 1024 + ni * 128;
#pragma unroll
    for (int i = 0; i < 4; ++i)
#pragma unroll
      for (int j = 0; j < 4; ++j)
#pragma unroll
        for (int r = 0; r < 4; ++r) {
          const int m = wm * 64 + i * 16 + lg * 4 + r;
          const int n = wn * 64 + j * 16 + lr;
          outp[(size_t)m * 1024 + n] = f2bf((acc[i][j][r] + biasv[j]) * oscale);
        }
  } else {
    // transpose chunks of 32 output-cols through LDS -> vbuf[b][o'][t]
    ushort_t* tb = (ushort_t*)tbuf;
#pragma unroll
    for (int c = 0; c < 4; ++c) {
      if (wn == (c >> 1)) {
#pragma unroll
        for (int jj = 0; jj < 2; ++jj) {
          const int j = (c & 1) * 2 + jj;
#pragma unroll
          for (int i = 0; i < 4; ++i)
#pragma unroll
            for (int r = 0; r < 4; ++r) {
              const int m = wm * 64 + i * 16 + lg * 4 + r;
              const int nl = jj * 16 + lr;
              tb[nl * 136 + m] = f2bf(acc[i][j][r] + biasv[j]);
            }
        }
      }
      __syncthreads();
      for (int u = tid; u < 512; u += 256) {
        const int nl = u >> 4, sg = u & 15;
        const int op = ni * 128 + c * 32 + nl - 1024;
        *(u32x4*)(vbuf + ((size_t)b * 512 + op) * 1024 + mi * 128 + sg * 8) =
            *(const u32x4*)(tb + nl * 136 + sg * 8);
      }
      __syncthreads();
    }
  }
}

// ---------------- flash attention (round-6 exact body; XCD-aware 1D launch) --------
// Q,K from qkT[b][t][h*64+d] (K at +512); V from vbuf[b][h*64+d][s]; out attnT.
// 1024 blocks 1D; decode puts all 8 qt-blocks of one (h,b) on one XCD (bid%8).
#define PSTR 68
__global__ __launch_bounds__(256) void k_attn(const ushort_t* __restrict__ qkT,
                                              const ushort_t* __restrict__ vbuf,
                                              ushort_t* __restrict__ attnT) {
  const int bid = blockIdx.x;
  const int xcd = bid & 7;
  const int qt  = (bid >> 3) & 7;
  const int hb  = ((bid >> 6) << 3) | xcd;   // 0..127, constant per XCD group
  const int h   = hb & 7, b = hb >> 3;
  const int tid = threadIdx.x, lane = tid & 63, w = tid >> 6;
  const int lr = lane & 15, lg = lane >> 4;

  __shared__ __align__(16) ushort_t Ks[64 * PSTR];
  __shared__ __align__(16) ushort_t Vs[64 * PSTR];
  __shared__ __align__(16) ushort_t Ps[4 * 32 * PSTR];

  // Q fragments in registers: rows qt*128 + w*32 + tI*16 + lr, d = kI*32 + lg*8
  bf16x8 aq[2][2];
#pragma unroll
  for (int tI = 0; tI < 2; ++tI) {
    const int t = qt * 128 + w * 32 + tI * 16 + lr;
    const ushort_t* qp = qkT + ((size_t)b * 1024 + t) * 1024 + h * 64 + lg * 8;
    aq[tI][0] = *(const bf16x8*)(qp);
    aq[tI][1] = *(const bf16x8*)(qp + 32);
  }

  f32x4 oacc[2][4] = {};
  float lrun[2][4] = {};

  const size_t vbase = ((size_t)b * 512 + h * 64) * 1024;
  const size_t kbase = (size_t)b * 1024 * 1024 + 512 + h * 64;
  ushort_t* Pw = Ps + w * 32 * PSTR;

  const int srow = tid >> 3, sseg = tid & 7;    // rows srow, srow+32
  u32x4 kr0, kr1, vr0, vr1;

  // prologue: stage tile 0
  kr0 = *(const u32x4*)(qkT + kbase + (size_t)srow * 1024 + sseg * 8);
  kr1 = *(const u32x4*)(qkT + kbase + (size_t)(srow + 32) * 1024 + sseg * 8);
  vr0 = *(const u32x4*)(vbuf + vbase + (size_t)srow * 1024 + sseg * 8);
  vr1 = *(const u32x4*)(vbuf + vbase + (size_t)(srow + 32) * 1024 + sseg * 8);
  *(u32x4*)(Ks + srow * PSTR + sseg * 8) = kr0;
  *(u32x4*)(Ks + (srow + 32) * PSTR + sseg * 8) = kr1;
  *(u32x4*)(Vs + srow * PSTR + sseg * 8) = vr0;
  *(u32x4*)(Vs + (srow + 32) * PSTR + sseg * 8) = vr1;
  __syncthreads();

  for (int st = 0; st < 16; ++st) {
    if (st < 15) {                    // issue next-tile loads before compute
      const int s0n = (st + 1) * 64;
      kr0 = *(const u32x4*)(qkT + kbase + (size_t)(s0n + srow) * 1024 + sseg * 8);
      kr1 = *(const u32x4*)(qkT + kbase + (size_t)(s0n + srow + 32) * 1024 + sseg * 8);
      vr0 = *(const u32x4*)(vbuf + vbase + (size_t)srow * 1024 + s0n + sseg * 8);
      vr1 = *(const u32x4*)(vbuf + vbase + (size_t)(srow + 32) * 1024 + s0n + sseg * 8);
    }

    // QK^T: S[t][s], 32x64 per wave (K pre-scaled by 0.125*log2e)
    f32x4 sacc[2][4] = {};
    __builtin_amdgcn_s_setprio(1);
#pragma unroll
    for (int sI = 0; sI < 4; ++sI) {
      const bf16x8 bk0 = *(const bf16x8*)(Ks + (sI * 16 + lr) * PSTR + lg * 8);
      const bf16x8 bk1 = *(const bf16x8*)(Ks + (sI * 16 + lr) * PSTR + 32 + lg * 8);
#pragma unroll
      for (int tI = 0; tI < 2; ++tI) {
        sacc[tI][sI] = mfma_bf16(aq[tI][0], bk0, sacc[tI][sI]);
        sacc[tI][sI] = mfma_bf16(aq[tI][1], bk1, sacc[tI][sI]);
      }
    }
    __builtin_amdgcn_s_setprio(0);

    // softmax numerator: p = exp2(s); in-lane partial row-sums only
#pragma unroll
    for (int tI = 0; tI < 2; ++tI)
#pragma unroll
      for (int sI = 0; sI < 4; ++sI)
#pragma unroll
        for (int r = 0; r < 4; ++r)
          sacc[tI][sI][r] = __builtin_amdgcn_exp2f(sacc[tI][sI][r]);
#pragma unroll
    for (int tI = 0; tI < 2; ++tI)
#pragma unroll
      for (int r = 0; r < 4; ++r)
        lrun[tI][r] += (sacc[tI][0][r] + sacc[tI][1][r]) + (sacc[tI][2][r] + sacc[tI][3][r]);

    // P -> per-wave LDS via packed bf16 converts
#pragma unroll
    for (int tI = 0; tI < 2; ++tI)
#pragma unroll
      for (int r = 0; r < 4; ++r) {
        const int rb = (tI * 16 + lg * 4 + r) * PSTR;
        const uint_t u0 = cvt_pk_bf16(sacc[tI][0][r], sacc[tI][1][r]);
        const uint_t u1 = cvt_pk_bf16(sacc[tI][2][r], sacc[tI][3][r]);
        Pw[rb + lr]      = (ushort_t)u0;
        Pw[rb + lr + 16] = (ushort_t)(u0 >> 16);
        Pw[rb + lr + 32] = (ushort_t)u1;
        Pw[rb + lr + 48] = (ushort_t)(u1 >> 16);
      }

    // PV: O[t][d] += P[t][s] * V[d][s]
#pragma unroll
    for (int tI = 0; tI < 2; ++tI) {
      const bf16x8 ap0 = *(const bf16x8*)(Pw + (tI * 16 + lr) * PSTR + lg * 8);
      const bf16x8 ap1 = *(const bf16x8*)(Pw + (tI * 16 + lr) * PSTR + 32 + lg * 8);
      __builtin_amdgcn_s_setprio(1);
#pragma unroll
      for (int dI = 0; dI < 4; ++dI) {
        const bf16x8 bv0 = *(const bf16x8*)(Vs + (dI * 16 + lr) * PSTR + lg * 8);
        const bf16x8 bv1 = *(const bf16x8*)(Vs + (dI * 16 + lr) * PSTR + 32 + lg * 8);
        oacc[tI][dI] = mfma_bf16(ap0, bv0, oacc[tI][dI]);
        oacc[tI][dI] = mfma_bf16(ap1, bv1, oacc[tI][dI]);
      }
      __builtin_amdgcn_s_setprio(0);
    }

    if (st < 15) {                    // block-uniform
      __syncthreads();                // all waves done reading Ks/Vs (full drain)
      *(u32x4*)(Ks + srow * PSTR + sseg * 8) = kr0;
      *(u32x4*)(Ks + (srow + 32) * PSTR + sseg * 8) = kr1;
      *(u32x4*)(Vs + srow * PSTR + sseg * 8) = vr0;
      *(u32x4*)(Vs + (srow + 32) * PSTR + sseg * 8) = vr1;
      __syncthreads();                // new tile visible
    }
  }

  // epilogue: cross-lane l reduce (deferred), O /= l, write attnT[b][t][h*64+d]
  float inv[2][4];
#pragma unroll
  for (int tI = 0; tI < 2; ++tI)
#pragma unroll
    for (int r = 0; r < 4; ++r) {
      float sum = lrun[tI][r];
      sum += __shfl_xor(sum, 1);
      sum += __shfl_xor(sum, 2);
      sum += __shfl_xor(sum, 4);
      sum += __shfl_xor(sum, 8);
      inv[tI][r] = 1.f / sum;
    }
#pragma unroll
  for (int tI = 0; tI < 2; ++tI)
#pragma unroll
    for (int dI = 0; dI < 4; ++dI)
#pragma unroll
      for (int r = 0; r < 4; ++r) {
        const int t = qt * 128 + w * 32 + tI * 16 + lg * 4 + r;
        attnT[((size_t)b * 1024 + t) * 512 + h * 64 + dI * 16 + lr] =
            f2bf(oacc[tI][dI][r] * inv[tI][r]);
      }
}

// ---------------- proj GEMM + bias + residual -> out (b, c, t) fp32 (round-6 exact) ----
__global__ __launch_bounds__(256) void k_proj(const ushort_t* __restrict__ attnT,
                                              const ushort_t* __restrict__ Wbf,
                                              const float* __restrict__ bias,
                                              const float* __restrict__ xres,
                                              float* __restrict__ outp) {
  const int mi = blockIdx.x, ni = blockIdx.y, b = blockIdx.z;
  const int tid = threadIdx.x, lane = tid & 63, w = tid >> 6;
  const int wm = w >> 1, wn = w & 1;
  const int lr = lane & 15, lg = lane >> 4;

  __shared__ __align__(16) ushort_t As[128 * 40];
  __shared__ __align__(16) ushort_t Bs[128 * 40];
  __shared__ __align__(16) float tbuf[32 * 132];

  const ushort_t* Ap = attnT + (size_t)b * 1024 * 512 + (size_t)mi * 128 * 512;
  const ushort_t* Bp = Wbf + (size_t)ni * 128 * 512;

  const int row0 = tid >> 2, seg = tid & 3;
  u32x4 ra0, ra1, rb0, rb1;

  ra0 = *(const u32x4*)(Ap + (size_t)row0 * 512 + seg * 8);
  ra1 = *(const u32x4*)(Ap + (size_t)(row0 + 64) * 512 + seg * 8);
  rb0 = *(const u32x4*)(Bp + (size_t)row0 * 512 + seg * 8);
  rb1 = *(const u32x4*)(Bp + (size_t)(row0 + 64) * 512 + seg * 8);
  *(u32x4*)(As + row0 * 40 + seg * 8) = ra0;
  *(u32x4*)(As + (row0 + 64) * 40 + seg * 8) = ra1;
  *(u32x4*)(Bs + row0 * 40 + seg * 8) = rb0;
  *(u32x4*)(Bs + (row0 + 64) * 40 + seg * 8) = rb1;
  __syncthreads();

  f32x4 acc[4][4] = {};

  for (int kt = 0; kt < 16; ++kt) {
    if (kt < 15) {
      const int k0n = (kt + 1) * 32;
      ra0 = *(const u32x4*)(Ap + (size_t)row0 * 512 + k0n + seg * 8);
      ra1 = *(const u32x4*)(Ap + (size_t)(row0 + 64) * 512 + k0n + seg * 8);
      rb0 = *(const u32x4*)(Bp + (size_t)row0 * 512 + k0n + seg * 8);
      rb1 = *(const u32x4*)(Bp + (size_t)(row0 + 64) * 512 + k0n + seg * 8);
    }
    bf16x8 af[4], bfv[4];
#pragma unroll
    for (int i = 0; i < 4; ++i)
      af[i] = *(const bf16x8*)(As + (wm * 64 + i * 16 + lr) * 40 + lg * 8);
#pragma unroll
    for (int j = 0; j < 4; ++j)
      bfv[j] = *(const bf16x8*)(Bs + (wn * 64 + j * 16 + lr) * 40 + lg * 8);
    __builtin_amdgcn_s_setprio(1);
#pragma unroll
    for (int i = 0; i < 4; ++i)
#pragma unroll
      for (int j = 0; j < 4; ++j)
        acc[i][j] = mfma_bf16(af[i], bfv[j], acc[i][j]);
    __builtin_amdgcn_s_setprio(0);
    if (kt < 15) {
      __syncthreads();
      *(u32x4*)(As + row0 * 40 + seg * 8) = ra0;
      *(u32x4*)(As + (row0 + 64) * 40 + seg * 8) = ra1;
      *(u32x4*)(Bs + row0 * 40 + seg * 8) = rb0;
      *(u32x4*)(Bs + (row0 + 64) * 40 + seg * 8) = rb1;
      __syncthreads();
    }
  }

  float biasv[4];
#pragma unroll
  for (int j = 0; j < 4; ++j) biasv[j] = bias[ni * 128 + wn * 64 + j * 16 + lr];

  // transpose (t,o)->(o,t) through LDS in 32-col chunks, add residual, fp32 out
#pragma unroll
  for (int c = 0; c < 4; ++c) {
    if (wn == (c >> 1)) {
#pragma unroll
      for (int jj = 0; jj < 2; ++jj) {
        const int j = (c & 1) * 2 + jj;
#pragma unroll
        for (int i = 0; i < 4; ++i)
#pragma unroll
          for (int r = 0; r < 4; ++r) {
            const int m = wm * 64 + i * 16 + lg * 4 + r;
            const int nl = jj * 16 + lr;
            tbuf[nl * 132 + m] = acc[i][j][r] + biasv[j];
          }
      }
    }
    __syncthreads();
    for (int u = tid; u < 1024; u += 256) {
      const int nl = u >> 5, sg = u & 31;
      const int o = ni * 128 + c * 32 + nl;
      const size_t idx = ((size_t)b * 512 + o) * 1024 + mi * 128 + sg * 4;
      const f32x4 t = *(const f32x4*)(tbuf + nl * 132 + sg * 4);
      const f32x4 xr = *(const f32x4*)(xres + idx);
      f32x4 ov = t + xr;
      *(f32x4*)(outp + idx) = ov;
    }
    __syncthreads();
  }
}

extern "C" void kernel_launch(void* const* d_in, const int* in_sizes, int n_in,
                              void* d_out, int out_size, void* d_ws, size_t ws_size,
                              hipStream_t stream) {
  (void)in_sizes; (void)n_in; (void)out_size; (void)ws_size;
  const float* x      = (const float*)d_in[0];
  const float* gsc    = (const float*)d_in[1];
  const float* gbi    = (const float*)d_in[2];
  const float* qkv_w  = (const float*)d_in[3];
  const float* qkv_b  = (const float*)d_in[4];
  const float* proj_w = (const float*)d_in[5];
  const float* proj_b = (const float*)d_in[6];
  float* out = (float*)d_out;

  char* ws = (char*)d_ws;
  ushort_t* xnT   = (ushort_t*)(ws);               // (16,1024,512) bf16  16 MiB
  ushort_t* qkT   = (ushort_t*)(ws + 16777216);    // (16,1024,1024) bf16 32 MiB
  ushort_t* vbuf  = (ushort_t*)(ws + 50331648);    // (16,512,1024) bf16  16 MiB
  ushort_t* attnT = (ushort_t*)(ws + 67108864);    // (16,1024,512) bf16  16 MiB
  ushort_t* qwbf  = (ushort_t*)(ws + 83886080);    // (1536,512) bf16
  ushort_t* pwbf  = (ushort_t*)(ws + 85458944);    // (512,512) bf16

  k_convert<<<768, 256, 0, stream>>>(qkv_w, qwbf, 1536 * 512);
  k_convert<<<256, 256, 0, stream>>>(proj_w, pwbf, 512 * 512);
  k_gn<<<dim3(32, 16), 256, 0, stream>>>(x, gsc, gbi, xnT);
  k_qkv<<<dim3(8, 12, 16), 256, 0, stream>>>(xnT, qwbf, qkv_b, qkT, vbuf);
  k_attn<<<1024, 256, 0, stream>>>(qkT, vbuf, attnT);
  k_proj<<<dim3(8, 4, 16), 256, 0, stream>>>(attnT, pwbf, proj_b, x, out);
}

// Round 10
// 238.732 us; speedup vs baseline: 1.0397x; 1.0397x over previous
//
#include <hip/hip_runtime.h>

typedef unsigned short ushort_t;
typedef unsigned int uint_t;
typedef __bf16 bf16x8 __attribute__((ext_vector_type(8)));
typedef float f32x4 __attribute__((ext_vector_type(4)));
typedef uint_t u32x4 __attribute__((ext_vector_type(4)));
typedef uint_t u32x2 __attribute__((ext_vector_type(2)));

// B=16, C=512, T=1024, NH=8, D=64, groups=32 (16 ch/group)
// K is pre-scaled by 0.125*log2(e) at QKV time so attn softmax is exp2(raw).
// Sync discipline: __syncthreads ONLY, round-6 protocol everywhere.
// Round-10 change (k_attn only): swapped-operand QK^T -> lane holds S^T
// (4 consecutive s per reg quad) -> P stored via 8 ds_write_b64 instead of
// 32 ds_write_b16; softmax row-sum becomes in-lane; LDS ops/tile 56 -> 32.

static __device__ __forceinline__ ushort_t f2bf(float f) {
  union { float f; uint_t u; } v; v.f = f;
  uint_t r = v.u + 0x7FFFu + ((v.u >> 16) & 1u);
  return (ushort_t)(r >> 16);
}

static __device__ __forceinline__ uint_t cvt_pk_bf16(float lo, float hi) {
  uint_t r;
  asm("v_cvt_pk_bf16_f32 %0, %1, %2" : "=v"(r) : "v"(lo), "v"(hi));
  return r;
}

static __device__ __forceinline__ f32x4 mfma_bf16(bf16x8 a, bf16x8 b, f32x4 c) {
  return __builtin_amdgcn_mfma_f32_16x16x32_bf16(a, b, c, 0, 0, 0);
}

// ---------------- fp32 -> bf16 convert ----------------
__global__ __launch_bounds__(256) void k_convert(const float* __restrict__ src,
                                                 ushort_t* __restrict__ dst, int n) {
  int i = (blockIdx.x * 256 + threadIdx.x) * 4;
  if (i >= n) return;
  f32x4 v = *(const f32x4*)(src + i);
  u32x2 o;
  o[0] = (uint_t)f2bf(v[0]) | ((uint_t)f2bf(v[1]) << 16);
  o[1] = (uint_t)f2bf(v[2]) | ((uint_t)f2bf(v[3]) << 16);
  *(u32x2*)(dst + i) = o;
}

// ---------------- GroupNorm + transpose -> xnT (b, t, c) bf16 (round-2 exact) ----
__global__ __launch_bounds__(256) void k_gn(const float* __restrict__ x,
                                            const float* __restrict__ gsc,
                                            const float* __restrict__ gbi,
                                            ushort_t* __restrict__ xnT) {
  const int g = blockIdx.x, b = blockIdx.y;
  const int tid = threadIdx.x;
  const float* xp = x + ((size_t)b * 512 + g * 16) * 1024;

  float s = 0.f, q = 0.f;
#pragma unroll
  for (int i = 0; i < 16; ++i) {
    f32x4 v = *(const f32x4*)(xp + (tid + i * 256) * 4);
    s += v[0] + v[1] + v[2] + v[3];
    q += v[0]*v[0] + v[1]*v[1] + v[2]*v[2] + v[3]*v[3];
  }
#pragma unroll
  for (int off = 32; off > 0; off >>= 1) { s += __shfl_xor(s, off); q += __shfl_xor(q, off); }

  __shared__ float rs[4], rq[4], ssc[16], sbi[16], stats[2];
  if ((tid & 63) == 0) { rs[tid >> 6] = s; rq[tid >> 6] = q; }
  if (tid < 16) { ssc[tid] = gsc[g * 16 + tid]; sbi[tid] = gbi[g * 16 + tid]; }
  __syncthreads();
  if (tid == 0) {
    float S = rs[0] + rs[1] + rs[2] + rs[3];
    float Q = rq[0] + rq[1] + rq[2] + rq[3];
    float mean = S * (1.f / 16384.f);
    float var  = Q * (1.f / 16384.f) - mean * mean;
    stats[0] = mean; stats[1] = rsqrtf(var + 1e-5f);
  }
  __syncthreads();
  const float mean = stats[0], rstd = stats[1];

#pragma unroll
  for (int i = 0; i < 8; ++i) {
    int u = tid + i * 256;          // 2048 units: (t, half)
    int t = u >> 1, half = u & 1;
    union { ushort_t us[8]; u32x4 v4; } o;
#pragma unroll
    for (int j = 0; j < 8; ++j) {
      int c = half * 8 + j;
      float v = (xp[(size_t)c * 1024 + t] - mean) * rstd * ssc[c] + sbi[c];
      o.us[j] = f2bf(v);
    }
    *(u32x4*)(xnT + ((size_t)b * 1024 + t) * 512 + g * 16 + half * 8) = o.v4;
  }
}

// ---------------- QKV GEMM (round-6 exact): D[t][o] = sum_c xnT[b][t][c]*W[o][c] ----
__global__ __launch_bounds__(256) void k_qkv(const ushort_t* __restrict__ xnT,
                                             const ushort_t* __restrict__ Wbf,
                                             const float* __restrict__ bias,
                                             ushort_t* __restrict__ qkT,
                                             ushort_t* __restrict__ vbuf) {
  const int mi = blockIdx.x, ni = blockIdx.y, b = blockIdx.z;
  const int tid = threadIdx.x, lane = tid & 63, w = tid >> 6;
  const int wm = w >> 1, wn = w & 1;
  const int lr = lane & 15, lg = lane >> 4;

  __shared__ __align__(16) ushort_t As[128 * 40];
  __shared__ __align__(16) ushort_t Bs[128 * 40];
  __shared__ __align__(16) float tbuf[32 * 132];

  const ushort_t* Ap = xnT + (size_t)b * 1024 * 512 + (size_t)mi * 128 * 512;
  const ushort_t* Bp = Wbf + (size_t)ni * 128 * 512;

  const int row0 = tid >> 2, seg = tid & 3;
  u32x4 ra0, ra1, rb0, rb1;

  // prologue: stage kt=0 (load + LDS write + barrier)
  ra0 = *(const u32x4*)(Ap + (size_t)row0 * 512 + seg * 8);
  ra1 = *(const u32x4*)(Ap + (size_t)(row0 + 64) * 512 + seg * 8);
  rb0 = *(const u32x4*)(Bp + (size_t)row0 * 512 + seg * 8);
  rb1 = *(const u32x4*)(Bp + (size_t)(row0 + 64) * 512 + seg * 8);
  *(u32x4*)(As + row0 * 40 + seg * 8) = ra0;
  *(u32x4*)(As + (row0 + 64) * 40 + seg * 8) = ra1;
  *(u32x4*)(Bs + row0 * 40 + seg * 8) = rb0;
  *(u32x4*)(Bs + (row0 + 64) * 40 + seg * 8) = rb1;
  __syncthreads();

  f32x4 acc[4][4] = {};

  for (int kt = 0; kt < 16; ++kt) {
    if (kt < 15) {                    // issue next-tile loads before compute
      const int k0n = (kt + 1) * 32;
      ra0 = *(const u32x4*)(Ap + (size_t)row0 * 512 + k0n + seg * 8);
      ra1 = *(const u32x4*)(Ap + (size_t)(row0 + 64) * 512 + k0n + seg * 8);
      rb0 = *(const u32x4*)(Bp + (size_t)row0 * 512 + k0n + seg * 8);
      rb1 = *(const u32x4*)(Bp + (size_t)(row0 + 64) * 512 + k0n + seg * 8);
    }
    bf16x8 af[4], bfv[4];
#pragma unroll
    for (int i = 0; i < 4; ++i)
      af[i] = *(const bf16x8*)(As + (wm * 64 + i * 16 + lr) * 40 + lg * 8);
#pragma unroll
    for (int j = 0; j < 4; ++j)
      bfv[j] = *(const bf16x8*)(Bs + (wn * 64 + j * 16 + lr) * 40 + lg * 8);
    __builtin_amdgcn_s_setprio(1);
#pragma unroll
    for (int i = 0; i < 4; ++i)
#pragma unroll
      for (int j = 0; j < 4; ++j)
        acc[i][j] = mfma_bf16(af[i], bfv[j], acc[i][j]);
    __builtin_amdgcn_s_setprio(0);
    if (kt < 15) {                    // block-uniform condition
      __syncthreads();                // all waves done reading As/Bs (full drain)
      *(u32x4*)(As + row0 * 40 + seg * 8) = ra0;
      *(u32x4*)(As + (row0 + 64) * 40 + seg * 8) = ra1;
      *(u32x4*)(Bs + row0 * 40 + seg * 8) = rb0;
      *(u32x4*)(Bs + (row0 + 64) * 40 + seg * 8) = rb1;
      __syncthreads();                // new tile visible
    }
  }

  float biasv[4];
#pragma unroll
  for (int j = 0; j < 4; ++j) biasv[j] = bias[ni * 128 + wn * 64 + j * 16 + lr];

  if (ni < 8) {
    // natural (t, o) write; K block (ni 4..7) pre-scaled for exp2 softmax
    const float oscale = (ni >= 4) ? 0.1803368801f : 1.0f;
    ushort_t* outp = qkT + ((size_t)b * 1024 + mi * 128) * 1024 + ni * 128;
#pragma unroll
    for (int i = 0; i < 4; ++i)
#pragma unroll
      for (int j = 0; j < 4; ++j)
#pragma unroll
        for (int r = 0; r < 4; ++r) {
          const int m = wm * 64 + i * 16 + lg * 4 + r;
          const int n = wn * 64 + j * 16 + lr;
          outp[(size_t)m * 1024 + n] = f2bf((acc[i][j][r] + biasv[j]) * oscale);
        }
  } else {
    // transpose chunks of 32 output-cols through LDS -> vbuf[b][o'][t]
    ushort_t* tb = (ushort_t*)tbuf;
#pragma unroll
    for (int c = 0; c < 4; ++c) {
      if (wn == (c >> 1)) {
#pragma unroll
        for (int jj = 0; jj < 2; ++jj) {
          const int j = (c & 1) * 2 + jj;
#pragma unroll
          for (int i = 0; i < 4; ++i)
#pragma unroll
            for (int r = 0; r < 4; ++r) {
              const int m = wm * 64 + i * 16 + lg * 4 + r;
              const int nl = jj * 16 + lr;
              tb[nl * 136 + m] = f2bf(acc[i][j][r] + biasv[j]);
            }
        }
      }
      __syncthreads();
      for (int u = tid; u < 512; u += 256) {
        const int nl = u >> 4, sg = u & 15;
        const int op = ni * 128 + c * 32 + nl - 1024;
        *(u32x4*)(vbuf + ((size_t)b * 512 + op) * 1024 + mi * 128 + sg * 8) =
            *(const u32x4*)(tb + nl * 136 + sg * 8);
      }
      __syncthreads();
    }
  }
}

// ---------------- flash attention (swapped QK^T; XCD-aware 1D launch) --------------
// Q,K from qkT[b][t][h*64+d] (K at +512); V from vbuf[b][h*64+d][s]; out attnT.
// 1024 blocks 1D; decode puts all 8 qt-blocks of one (h,b) on one XCD (bid%8).
#define PSTR 68
__global__ __launch_bounds__(256) void k_attn(const ushort_t* __restrict__ qkT,
                                              const ushort_t* __restrict__ vbuf,
                                              ushort_t* __restrict__ attnT) {
  const int bid = blockIdx.x;
  const int xcd = bid & 7;
  const int qt  = (bid >> 3) & 7;
  const int hb  = ((bid >> 6) << 3) | xcd;   // 0..127, constant per XCD group
  const int h   = hb & 7, b = hb >> 3;
  const int tid = threadIdx.x, lane = tid & 63, w = tid >> 6;
  const int lr = lane & 15, lg = lane >> 4;

  __shared__ __align__(16) ushort_t Ks[64 * PSTR];
  __shared__ __align__(16) ushort_t Vs[64 * PSTR];
  __shared__ __align__(16) ushort_t Ps[4 * 32 * PSTR];

  // Q fragments in registers: rows qt*128 + w*32 + tI*16 + lr, d = kI*32 + lg*8
  bf16x8 aq[2][2];
#pragma unroll
  for (int tI = 0; tI < 2; ++tI) {
    const int t = qt * 128 + w * 32 + tI * 16 + lr;
    const ushort_t* qp = qkT + ((size_t)b * 1024 + t) * 1024 + h * 64 + lg * 8;
    aq[tI][0] = *(const bf16x8*)(qp);
    aq[tI][1] = *(const bf16x8*)(qp + 32);
  }

  f32x4 oacc[2][4] = {};
  float lrun[2] = {0.f, 0.f};        // per-lane partial row-sum for t = tI*16+lr

  const size_t vbase = ((size_t)b * 512 + h * 64) * 1024;
  const size_t kbase = (size_t)b * 1024 * 1024 + 512 + h * 64;
  ushort_t* Pw = Ps + w * 32 * PSTR;

  const int srow = tid >> 3, sseg = tid & 7;    // rows srow, srow+32
  u32x4 kr0, kr1, vr0, vr1;

  // prologue: stage tile 0
  kr0 = *(const u32x4*)(qkT + kbase + (size_t)srow * 1024 + sseg * 8);
  kr1 = *(const u32x4*)(qkT + kbase + (size_t)(srow + 32) * 1024 + sseg * 8);
  vr0 = *(const u32x4*)(vbuf + vbase + (size_t)srow * 1024 + sseg * 8);
  vr1 = *(const u32x4*)(vbuf + vbase + (size_t)(srow + 32) * 1024 + sseg * 8);
  *(u32x4*)(Ks + srow * PSTR + sseg * 8) = kr0;
  *(u32x4*)(Ks + (srow + 32) * PSTR + sseg * 8) = kr1;
  *(u32x4*)(Vs + srow * PSTR + sseg * 8) = vr0;
  *(u32x4*)(Vs + (srow + 32) * PSTR + sseg * 8) = vr1;
  __syncthreads();

  for (int st = 0; st < 16; ++st) {
    if (st < 15) {                    // issue next-tile loads before compute
      const int s0n = (st + 1) * 64;
      kr0 = *(const u32x4*)(qkT + kbase + (size_t)(s0n + srow) * 1024 + sseg * 8);
      kr1 = *(const u32x4*)(qkT + kbase + (size_t)(s0n + srow + 32) * 1024 + sseg * 8);
      vr0 = *(const u32x4*)(vbuf + vbase + (size_t)srow * 1024 + s0n + sseg * 8);
      vr1 = *(const u32x4*)(vbuf + vbase + (size_t)(srow + 32) * 1024 + s0n + sseg * 8);
    }

    // Swapped QK^T: sacc[tI][sI] = S^T fragment,
    // lane holds s = sI*16 + lg*4 + r (r=0..3), t = tI*16 + lr.
    f32x4 sacc[2][4] = {};
    __builtin_amdgcn_s_setprio(1);
#pragma unroll
    for (int sI = 0; sI < 4; ++sI) {
      const bf16x8 bk0 = *(const bf16x8*)(Ks + (sI * 16 + lr) * PSTR + lg * 8);
      const bf16x8 bk1 = *(const bf16x8*)(Ks + (sI * 16 + lr) * PSTR + 32 + lg * 8);
#pragma unroll
      for (int tI = 0; tI < 2; ++tI) {
        sacc[tI][sI] = mfma_bf16(bk0, aq[tI][0], sacc[tI][sI]);
        sacc[tI][sI] = mfma_bf16(bk1, aq[tI][1], sacc[tI][sI]);
      }
    }
    __builtin_amdgcn_s_setprio(0);

    // softmax numerator: p = exp2(s); in-lane partial sums (16 values per tI)
#pragma unroll
    for (int tI = 0; tI < 2; ++tI)
#pragma unroll
      for (int sI = 0; sI < 4; ++sI)
#pragma unroll
        for (int r = 0; r < 4; ++r)
          sacc[tI][sI][r] = __builtin_amdgcn_exp2f(sacc[tI][sI][r]);
#pragma unroll
    for (int tI = 0; tI < 2; ++tI) {
      float a0 = (sacc[tI][0][0] + sacc[tI][0][1]) + (sacc[tI][0][2] + sacc[tI][0][3]);
      float a1 = (sacc[tI][1][0] + sacc[tI][1][1]) + (sacc[tI][1][2] + sacc[tI][1][3]);
      float a2 = (sacc[tI][2][0] + sacc[tI][2][1]) + (sacc[tI][2][2] + sacc[tI][2][3]);
      float a3 = (sacc[tI][3][0] + sacc[tI][3][1]) + (sacc[tI][3][2] + sacc[tI][3][3]);
      lrun[tI] += (a0 + a1) + (a2 + a3);
    }

    // P -> per-wave LDS: 8 x ds_write_b64 (4 consecutive s per write)
    // P_lds[t = tI*16+lr][cols sI*16 + lg*4 .. +3]
#pragma unroll
    for (int tI = 0; tI < 2; ++tI)
#pragma unroll
      for (int sI = 0; sI < 4; ++sI) {
        u32x2 d;
        d[0] = cvt_pk_bf16(sacc[tI][sI][0], sacc[tI][sI][1]);
        d[1] = cvt_pk_bf16(sacc[tI][sI][2], sacc[tI][sI][3]);
        *(u32x2*)(Pw + (tI * 16 + lr) * PSTR + sI * 16 + lg * 4) = d;
      }

    // PV: O[t][d] += P[t][s] * V[d][s]   (fragment reads unchanged)
#pragma unroll
    for (int tI = 0; tI < 2; ++tI) {
      const bf16x8 ap0 = *(const bf16x8*)(Pw + (tI * 16 + lr) * PSTR + lg * 8);
      const bf16x8 ap1 = *(const bf16x8*)(Pw + (tI * 16 + lr) * PSTR + 32 + lg * 8);
      __builtin_amdgcn_s_setprio(1);
#pragma unroll
      for (int dI = 0; dI < 4; ++dI) {
        const bf16x8 bv0 = *(const bf16x8*)(Vs + (dI * 16 + lr) * PSTR + lg * 8);
        const bf16x8 bv1 = *(const bf16x8*)(Vs + (dI * 16 + lr) * PSTR + 32 + lg * 8);
        oacc[tI][dI] = mfma_bf16(ap0, bv0, oacc[tI][dI]);
        oacc[tI][dI] = mfma_bf16(ap1, bv1, oacc[tI][dI]);
      }
      __builtin_amdgcn_s_setprio(0);
    }

    if (st < 15) {                    // block-uniform
      __syncthreads();                // all waves done reading Ks/Vs (full drain)
      *(u32x4*)(Ks + srow * PSTR + sseg * 8) = kr0;
      *(u32x4*)(Ks + (srow + 32) * PSTR + sseg * 8) = kr1;
      *(u32x4*)(Vs + srow * PSTR + sseg * 8) = vr0;
      *(u32x4*)(Vs + (srow + 32) * PSTR + sseg * 8) = vr1;
      __syncthreads();                // new tile visible
    }
  }

  // epilogue: finish l across the four 16-lane groups, fetch per-output-row inv,
  // O /= l, write attnT[b][t][h*64+d]
  float inv[2][4];
#pragma unroll
  for (int tI = 0; tI < 2; ++tI) {
    float tot = lrun[tI];
    tot += __shfl_xor(tot, 16);
    tot += __shfl_xor(tot, 32);       // all lanes with same lr now hold total for t=tI*16+lr
#pragma unroll
    for (int r = 0; r < 4; ++r) {
      // output row t = tI*16 + lg*4 + r lives at source lane (lane&48)|(lg*4+r)
      inv[tI][r] = 1.f / __shfl(tot, (lane & 48) | (lg * 4 + r));
    }
  }
#pragma unroll
  for (int tI = 0; tI < 2; ++tI)
#pragma unroll
    for (int dI = 0; dI < 4; ++dI)
#pragma unroll
      for (int r = 0; r < 4; ++r) {
        const int t = qt * 128 + w * 32 + tI * 16 + lg * 4 + r;
        attnT[((size_t)b * 1024 + t) * 512 + h * 64 + dI * 16 + lr] =
            f2bf(oacc[tI][dI][r] * inv[tI][r]);
      }
}

// ---------------- proj GEMM + bias + residual -> out (b, c, t) fp32 (round-6 exact) ----
__global__ __launch_bounds__(256) void k_proj(const ushort_t* __restrict__ attnT,
                                              const ushort_t* __restrict__ Wbf,
                                              const float* __restrict__ bias,
                                              const float* __restrict__ xres,
                                              float* __restrict__ outp) {
  const int mi = blockIdx.x, ni = blockIdx.y, b = blockIdx.z;
  const int tid = threadIdx.x, lane = tid & 63, w = tid >> 6;
  const int wm = w >> 1, wn = w & 1;
  const int lr = lane & 15, lg = lane >> 4;

  __shared__ __align__(16) ushort_t As[128 * 40];
  __shared__ __align__(16) ushort_t Bs[128 * 40];
  __shared__ __align__(16) float tbuf[32 * 132];

  const ushort_t* Ap = attnT + (size_t)b * 1024 * 512 + (size_t)mi * 128 * 512;
  const ushort_t* Bp = Wbf + (size_t)ni * 128 * 512;

  const int row0 = tid >> 2, seg = tid & 3;
  u32x4 ra0, ra1, rb0, rb1;

  ra0 = *(const u32x4*)(Ap + (size_t)row0 * 512 + seg * 8);
  ra1 = *(const u32x4*)(Ap + (size_t)(row0 + 64) * 512 + seg * 8);
  rb0 = *(const u32x4*)(Bp + (size_t)row0 * 512 + seg * 8);
  rb1 = *(const u32x4*)(Bp + (size_t)(row0 + 64) * 512 + seg * 8);
  *(u32x4*)(As + row0 * 40 + seg * 8) = ra0;
  *(u32x4*)(As + (row0 + 64) * 40 + seg * 8) = ra1;
  *(u32x4*)(Bs + row0 * 40 + seg * 8) = rb0;
  *(u32x4*)(Bs + (row0 + 64) * 40 + seg * 8) = rb1;
  __syncthreads();

  f32x4 acc[4][4] = {};

  for (int kt = 0; kt < 16; ++kt) {
    if (kt < 15) {
      const int k0n = (kt + 1) * 32;
      ra0 = *(const u32x4*)(Ap + (size_t)row0 * 512 + k0n + seg * 8);
      ra1 = *(const u32x4*)(Ap + (size_t)(row0 + 64) * 512 + k0n + seg * 8);
      rb0 = *(const u32x4*)(Bp + (size_t)row0 * 512 + k0n + seg * 8);
      rb1 = *(const u32x4*)(Bp + (size_t)(row0 + 64) * 512 + k0n + seg * 8);
    }
    bf16x8 af[4], bfv[4];
#pragma unroll
    for (int i = 0; i < 4; ++i)
      af[i] = *(const bf16x8*)(As + (wm * 64 + i * 16 + lr) * 40 + lg * 8);
#pragma unroll
    for (int j = 0; j < 4; ++j)
      bfv[j] = *(const bf16x8*)(Bs + (wn * 64 + j * 16 + lr) * 40 + lg * 8);
    __builtin_amdgcn_s_setprio(1);
#pragma unroll
    for (int i = 0; i < 4; ++i)
#pragma unroll
      for (int j = 0; j < 4; ++j)
        acc[i][j] = mfma_bf16(af[i], bfv[j], acc[i][j]);
    __builtin_amdgcn_s_setprio(0);
    if (kt < 15) {
      __syncthreads();
      *(u32x4*)(As + row0 * 40 + seg * 8) = ra0;
      *(u32x4*)(As + (row0 + 64) * 40 + seg * 8) = ra1;
      *(u32x4*)(Bs + row0 * 40 + seg * 8) = rb0;
      *(u32x4*)(Bs + (row0 + 64) * 40 + seg * 8) = rb1;
      __syncthreads();
    }
  }

  float biasv[4];
#pragma unroll
  for (int j = 0; j < 4; ++j) biasv[j] = bias[ni * 128 + wn * 64 + j * 16 + lr];

  // transpose (t,o)->(o,t) through LDS in 32-col chunks, add residual, fp32 out
#pragma unroll
  for (int c = 0; c < 4; ++c) {
    if (wn == (c >> 1)) {
#pragma unroll
      for (int jj = 0; jj < 2; ++jj) {
        const int j = (c & 1) * 2 + jj;
#pragma unroll
        for (int i = 0; i < 4; ++i)
#pragma unroll
          for (int r = 0; r < 4; ++r) {
            const int m = wm * 64 + i * 16 + lg * 4 + r;
            const int nl = jj * 16 + lr;
            tbuf[nl * 132 + m] = acc[i][j][r] + biasv[j];
          }
      }
    }
    __syncthreads();
    for (int u = tid; u < 1024; u += 256) {
      const int nl = u >> 5, sg = u & 31;
      const int o = ni * 128 + c * 32 + nl;
      const size_t idx = ((size_t)b * 512 + o) * 1024 + mi * 128 + sg * 4;
      const f32x4 t = *(const f32x4*)(tbuf + nl * 132 + sg * 4);
      const f32x4 xr = *(const f32x4*)(xres + idx);
      f32x4 ov = t + xr;
      *(f32x4*)(outp + idx) = ov;
    }
    __syncthreads();
  }
}

extern "C" void kernel_launch(void* const* d_in, const int* in_sizes, int n_in,
                              void* d_out, int out_size, void* d_ws, size_t ws_size,
                              hipStream_t stream) {
  (void)in_sizes; (void)n_in; (void)out_size; (void)ws_size;
  const float* x      = (const float*)d_in[0];
  const float* gsc    = (const float*)d_in[1];
  const float* gbi    = (const float*)d_in[2];
  const float* qkv_w  = (const float*)d_in[3];
  const float* qkv_b  = (const float*)d_in[4];
  const float* proj_w = (const float*)d_in[5];
  const float* proj_b = (const float*)d_in[6];
  float* out = (float*)d_out;

  char* ws = (char*)d_ws;
  ushort_t* xnT   = (ushort_t*)(ws);               // (16,1024,512) bf16  16 MiB
  ushort_t* qkT   = (ushort_t*)(ws + 16777216);    // (16,1024,1024) bf16 32 MiB
  ushort_t* vbuf  = (ushort_t*)(ws + 50331648);    // (16,512,1024) bf16  16 MiB
  ushort_t* attnT = (ushort_t*)(ws + 67108864);    // (16,1024,512) bf16  16 MiB
  ushort_t* qwbf  = (ushort_t*)(ws + 83886080);    // (1536,512) bf16
  ushort_t* pwbf  = (ushort_t*)(ws + 85458944);    // (512,512) bf16

  k_convert<<<768, 256, 0, stream>>>(qkv_w, qwbf, 1536 * 512);
  k_convert<<<256, 256, 0, stream>>>(proj_w, pwbf, 512 * 512);
  k_gn<<<dim3(32, 16), 256, 0, stream>>>(x, gsc, gbi, xnT);
  k_qkv<<<dim3(8, 12, 16), 256, 0, stream>>>(xnT, qwbf, qkv_b, qkT, vbuf);
  k_attn<<<1024, 256, 0, stream>>>(qkT, vbuf, attnT);
  k_proj<<<dim3(8, 4, 16), 256, 0, stream>>>(attnT, pwbf, proj_b, x, out);
}

// Round 11
// 234.571 us; speedup vs baseline: 1.0582x; 1.0177x over previous
//
#include <hip/hip_runtime.h>

typedef unsigned short ushort_t;
typedef unsigned int uint_t;
typedef __bf16 bf16x8 __attribute__((ext_vector_type(8)));
typedef float f32x4 __attribute__((ext_vector_type(4)));
typedef uint_t u32x4 __attribute__((ext_vector_type(4)));
typedef uint_t u32x2 __attribute__((ext_vector_type(2)));

// B=16, C=512, T=1024, NH=8, D=64, groups=32 (16 ch/group)
// K is pre-scaled by 0.125*log2(e) at QKV time so attn softmax is exp2(raw).
// Sync discipline: __syncthreads ONLY.
// Round-11 change (k_qkv/k_proj only): global_load_lds width=16 staging into
// double-buffered LINEAR LDS tiles [128][32], ONE __syncthreads per K-step.
// Safety: loads for kt+1 target buf[cur^1] (last read at kt-1, drained by that
// iteration's __syncthreads); end-of-kt __syncthreads drains vmcnt(0) so the
// buffer is complete before any wave reads it. k_attn = round-10 verbatim.

static __device__ __forceinline__ ushort_t f2bf(float f) {
  union { float f; uint_t u; } v; v.f = f;
  uint_t r = v.u + 0x7FFFu + ((v.u >> 16) & 1u);
  return (ushort_t)(r >> 16);
}

static __device__ __forceinline__ uint_t cvt_pk_bf16(float lo, float hi) {
  uint_t r;
  asm("v_cvt_pk_bf16_f32 %0, %1, %2" : "=v"(r) : "v"(lo), "v"(hi));
  return r;
}

static __device__ __forceinline__ f32x4 mfma_bf16(bf16x8 a, bf16x8 b, f32x4 c) {
  return __builtin_amdgcn_mfma_f32_16x16x32_bf16(a, b, c, 0, 0, 0);
}

// async global->LDS, 16B per lane; LDS dest is wave-uniform base + lane*16B
static __device__ __forceinline__ void gload16(const ushort_t* g, ushort_t* l) {
  __builtin_amdgcn_global_load_lds(
      (const __attribute__((address_space(1))) uint_t*)g,
      (__attribute__((address_space(3))) uint_t*)l, 16, 0, 0);
}

// ---------------- fp32 -> bf16 convert ----------------
__global__ __launch_bounds__(256) void k_convert(const float* __restrict__ src,
                                                 ushort_t* __restrict__ dst, int n) {
  int i = (blockIdx.x * 256 + threadIdx.x) * 4;
  if (i >= n) return;
  f32x4 v = *(const f32x4*)(src + i);
  u32x2 o;
  o[0] = (uint_t)f2bf(v[0]) | ((uint_t)f2bf(v[1]) << 16);
  o[1] = (uint_t)f2bf(v[2]) | ((uint_t)f2bf(v[3]) << 16);
  *(u32x2*)(dst + i) = o;
}

// ---------------- GroupNorm + transpose -> xnT (b, t, c) bf16 (round-2 exact) ----
__global__ __launch_bounds__(256) void k_gn(const float* __restrict__ x,
                                            const float* __restrict__ gsc,
                                            const float* __restrict__ gbi,
                                            ushort_t* __restrict__ xnT) {
  const int g = blockIdx.x, b = blockIdx.y;
  const int tid = threadIdx.x;
  const float* xp = x + ((size_t)b * 512 + g * 16) * 1024;

  float s = 0.f, q = 0.f;
#pragma unroll
  for (int i = 0; i < 16; ++i) {
    f32x4 v = *(const f32x4*)(xp + (tid + i * 256) * 4);
    s += v[0] + v[1] + v[2] + v[3];
    q += v[0]*v[0] + v[1]*v[1] + v[2]*v[2] + v[3]*v[3];
  }
#pragma unroll
  for (int off = 32; off > 0; off >>= 1) { s += __shfl_xor(s, off); q += __shfl_xor(q, off); }

  __shared__ float rs[4], rq[4], ssc[16], sbi[16], stats[2];
  if ((tid & 63) == 0) { rs[tid >> 6] = s; rq[tid >> 6] = q; }
  if (tid < 16) { ssc[tid] = gsc[g * 16 + tid]; sbi[tid] = gbi[g * 16 + tid]; }
  __syncthreads();
  if (tid == 0) {
    float S = rs[0] + rs[1] + rs[2] + rs[3];
    float Q = rq[0] + rq[1] + rq[2] + rq[3];
    float mean = S * (1.f / 16384.f);
    float var  = Q * (1.f / 16384.f) - mean * mean;
    stats[0] = mean; stats[1] = rsqrtf(var + 1e-5f);
  }
  __syncthreads();
  const float mean = stats[0], rstd = stats[1];

#pragma unroll
  for (int i = 0; i < 8; ++i) {
    int u = tid + i * 256;          // 2048 units: (t, half)
    int t = u >> 1, half = u & 1;
    union { ushort_t us[8]; u32x4 v4; } o;
#pragma unroll
    for (int j = 0; j < 8; ++j) {
      int c = half * 8 + j;
      float v = (xp[(size_t)c * 1024 + t] - mean) * rstd * ssc[c] + sbi[c];
      o.us[j] = f2bf(v);
    }
    *(u32x4*)(xnT + ((size_t)b * 1024 + t) * 512 + g * 16 + half * 8) = o.v4;
  }
}

// ---------------- QKV GEMM: D[t][o] = sum_c xnT[b][t][c] * W[o][c] ----------------
// global_load_lds staging, double-buffered linear LDS [128][32], 1 sync/K-step.
__global__ __launch_bounds__(256) void k_qkv(const ushort_t* __restrict__ xnT,
                                             const ushort_t* __restrict__ Wbf,
                                             const float* __restrict__ bias,
                                             ushort_t* __restrict__ qkT,
                                             ushort_t* __restrict__ vbuf) {
  const int mi = blockIdx.x, ni = blockIdx.y, b = blockIdx.z;
  const int tid = threadIdx.x, lane = tid & 63, w = tid >> 6;
  const int wm = w >> 1, wn = w & 1;
  const int lr = lane & 15, lg = lane >> 4;

  __shared__ __align__(16) ushort_t As[2][4096];   // [128][32] linear
  __shared__ __align__(16) ushort_t Bs[2][4096];
  __shared__ __align__(16) float tbuf[32 * 132];

  const ushort_t* Ap = xnT + (size_t)b * 1024 * 512 + (size_t)mi * 128 * 512;
  const ushort_t* Bp = Wbf + (size_t)ni * 128 * 512;

  const int r0 = tid >> 2, sg = tid & 3;           // unit tid: row r0, col-seg sg
  const int wbase0 = w * 512;                      // LDS elem base, units 0..255
  const int wbase1 = 2048 + w * 512;               // units 256..511 (rows +64)

  // prologue: stage kt=0 into buf 0
  gload16(Ap + (size_t)r0 * 512 + sg * 8,        &As[0][wbase0]);
  gload16(Ap + (size_t)(r0 + 64) * 512 + sg * 8, &As[0][wbase1]);
  gload16(Bp + (size_t)r0 * 512 + sg * 8,        &Bs[0][wbase0]);
  gload16(Bp + (size_t)(r0 + 64) * 512 + sg * 8, &Bs[0][wbase1]);
  __syncthreads();                                 // vmcnt drained: buf0 ready

  f32x4 acc[4][4] = {};

  for (int kt = 0; kt < 16; ++kt) {
    const int cur = kt & 1;
    if (kt < 15) {                  // async loads for kt+1 into the other buffer
      const int k0n = (kt + 1) * 32;
      gload16(Ap + (size_t)r0 * 512 + k0n + sg * 8,        &As[cur ^ 1][wbase0]);
      gload16(Ap + (size_t)(r0 + 64) * 512 + k0n + sg * 8, &As[cur ^ 1][wbase1]);
      gload16(Bp + (size_t)r0 * 512 + k0n + sg * 8,        &Bs[cur ^ 1][wbase0]);
      gload16(Bp + (size_t)(r0 + 64) * 512 + k0n + sg * 8, &Bs[cur ^ 1][wbase1]);
    }
    bf16x8 af[4], bfv[4];
#pragma unroll
    for (int i = 0; i < 4; ++i)
      af[i] = *(const bf16x8*)(&As[cur][(wm * 64 + i * 16 + lr) * 32 + lg * 8]);
#pragma unroll
    for (int j = 0; j < 4; ++j)
      bfv[j] = *(const bf16x8*)(&Bs[cur][(wn * 64 + j * 16 + lr) * 32 + lg * 8]);
    __builtin_amdgcn_s_setprio(1);
#pragma unroll
    for (int i = 0; i < 4; ++i)
#pragma unroll
      for (int j = 0; j < 4; ++j)
        acc[i][j] = mfma_bf16(af[i], bfv[j], acc[i][j]);
    __builtin_amdgcn_s_setprio(0);
    __syncthreads();                // drains vmcnt (next buf ready) + all reads done
  }

  float biasv[4];
#pragma unroll
  for (int j = 0; j < 4; ++j) biasv[j] = bias[ni * 128 + wn * 64 + j * 16 + lr];

  if (ni < 8) {
    // natural (t, o) write; K block (ni 4..7) pre-scaled for exp2 softmax
    const float oscale = (ni >= 4) ? 0.1803368801f : 1.0f;
    ushort_t* outp = qkT + ((size_t)b * 1024 + mi * 128) * 1024 + ni * 128;
#pragma unroll
    for (int i = 0; i < 4; ++i)
#pragma unroll
      for (int j = 0; j < 4; ++j)
#pragma unroll
        for (int r = 0; r < 4; ++r) {
          const int m = wm * 64 + i * 16 + lg * 4 + r;
          const int n = wn * 64 + j * 16 + lr;
          outp[(size_t)m * 1024 + n] = f2bf((acc[i][j][r] + biasv[j]) * oscale);
        }
  } else {
    // transpose chunks of 32 output-cols through LDS -> vbuf[b][o'][t]
    ushort_t* tb = (ushort_t*)tbuf;
#pragma unroll
    for (int c = 0; c < 4; ++c) {
      if (wn == (c >> 1)) {
#pragma unroll
        for (int jj = 0; jj < 2; ++jj) {
          const int j = (c & 1) * 2 + jj;
#pragma unroll
          for (int i = 0; i < 4; ++i)
#pragma unroll
            for (int r = 0; r < 4; ++r) {
              const int m = wm * 64 + i * 16 + lg * 4 + r;
              const int nl = jj * 16 + lr;
              tb[nl * 136 + m] = f2bf(acc[i][j][r] + biasv[j]);
            }
        }
      }
      __syncthreads();
      for (int u = tid; u < 512; u += 256) {
        const int nl = u >> 4, sgx = u & 15;
        const int op = ni * 128 + c * 32 + nl - 1024;
        *(u32x4*)(vbuf + ((size_t)b * 512 + op) * 1024 + mi * 128 + sgx * 8) =
            *(const u32x4*)(tb + nl * 136 + sgx * 8);
      }
      __syncthreads();
    }
  }
}

// ---------------- flash attention (round-10 exact: swapped QK^T, XCD 1D launch) ----
#define PSTR 68
__global__ __launch_bounds__(256) void k_attn(const ushort_t* __restrict__ qkT,
                                              const ushort_t* __restrict__ vbuf,
                                              ushort_t* __restrict__ attnT) {
  const int bid = blockIdx.x;
  const int xcd = bid & 7;
  const int qt  = (bid >> 3) & 7;
  const int hb  = ((bid >> 6) << 3) | xcd;   // 0..127, constant per XCD group
  const int h   = hb & 7, b = hb >> 3;
  const int tid = threadIdx.x, lane = tid & 63, w = tid >> 6;
  const int lr = lane & 15, lg = lane >> 4;

  __shared__ __align__(16) ushort_t Ks[64 * PSTR];
  __shared__ __align__(16) ushort_t Vs[64 * PSTR];
  __shared__ __align__(16) ushort_t Ps[4 * 32 * PSTR];

  bf16x8 aq[2][2];
#pragma unroll
  for (int tI = 0; tI < 2; ++tI) {
    const int t = qt * 128 + w * 32 + tI * 16 + lr;
    const ushort_t* qp = qkT + ((size_t)b * 1024 + t) * 1024 + h * 64 + lg * 8;
    aq[tI][0] = *(const bf16x8*)(qp);
    aq[tI][1] = *(const bf16x8*)(qp + 32);
  }

  f32x4 oacc[2][4] = {};
  float lrun[2] = {0.f, 0.f};

  const size_t vbase = ((size_t)b * 512 + h * 64) * 1024;
  const size_t kbase = (size_t)b * 1024 * 1024 + 512 + h * 64;
  ushort_t* Pw = Ps + w * 32 * PSTR;

  const int srow = tid >> 3, sseg = tid & 7;
  u32x4 kr0, kr1, vr0, vr1;

  kr0 = *(const u32x4*)(qkT + kbase + (size_t)srow * 1024 + sseg * 8);
  kr1 = *(const u32x4*)(qkT + kbase + (size_t)(srow + 32) * 1024 + sseg * 8);
  vr0 = *(const u32x4*)(vbuf + vbase + (size_t)srow * 1024 + sseg * 8);
  vr1 = *(const u32x4*)(vbuf + vbase + (size_t)(srow + 32) * 1024 + sseg * 8);
  *(u32x4*)(Ks + srow * PSTR + sseg * 8) = kr0;
  *(u32x4*)(Ks + (srow + 32) * PSTR + sseg * 8) = kr1;
  *(u32x4*)(Vs + srow * PSTR + sseg * 8) = vr0;
  *(u32x4*)(Vs + (srow + 32) * PSTR + sseg * 8) = vr1;
  __syncthreads();

  for (int st = 0; st < 16; ++st) {
    if (st < 15) {
      const int s0n = (st + 1) * 64;
      kr0 = *(const u32x4*)(qkT + kbase + (size_t)(s0n + srow) * 1024 + sseg * 8);
      kr1 = *(const u32x4*)(qkT + kbase + (size_t)(s0n + srow + 32) * 1024 + sseg * 8);
      vr0 = *(const u32x4*)(vbuf + vbase + (size_t)srow * 1024 + s0n + sseg * 8);
      vr1 = *(const u32x4*)(vbuf + vbase + (size_t)(srow + 32) * 1024 + s0n + sseg * 8);
    }

    // Swapped QK^T: lane holds s = sI*16 + lg*4 + r, t = tI*16 + lr.
    f32x4 sacc[2][4] = {};
    __builtin_amdgcn_s_setprio(1);
#pragma unroll
    for (int sI = 0; sI < 4; ++sI) {
      const bf16x8 bk0 = *(const bf16x8*)(Ks + (sI * 16 + lr) * PSTR + lg * 8);
      const bf16x8 bk1 = *(const bf16x8*)(Ks + (sI * 16 + lr) * PSTR + 32 + lg * 8);
#pragma unroll
      for (int tI = 0; tI < 2; ++tI) {
        sacc[tI][sI] = mfma_bf16(bk0, aq[tI][0], sacc[tI][sI]);
        sacc[tI][sI] = mfma_bf16(bk1, aq[tI][1], sacc[tI][sI]);
      }
    }
    __builtin_amdgcn_s_setprio(0);

#pragma unroll
    for (int tI = 0; tI < 2; ++tI)
#pragma unroll
      for (int sI = 0; sI < 4; ++sI)
#pragma unroll
        for (int r = 0; r < 4; ++r)
          sacc[tI][sI][r] = __builtin_amdgcn_exp2f(sacc[tI][sI][r]);
#pragma unroll
    for (int tI = 0; tI < 2; ++tI) {
      float a0 = (sacc[tI][0][0] + sacc[tI][0][1]) + (sacc[tI][0][2] + sacc[tI][0][3]);
      float a1 = (sacc[tI][1][0] + sacc[tI][1][1]) + (sacc[tI][1][2] + sacc[tI][1][3]);
      float a2 = (sacc[tI][2][0] + sacc[tI][2][1]) + (sacc[tI][2][2] + sacc[tI][2][3]);
      float a3 = (sacc[tI][3][0] + sacc[tI][3][1]) + (sacc[tI][3][2] + sacc[tI][3][3]);
      lrun[tI] += (a0 + a1) + (a2 + a3);
    }

    // P -> per-wave LDS: 8 x ds_write_b64
#pragma unroll
    for (int tI = 0; tI < 2; ++tI)
#pragma unroll
      for (int sI = 0; sI < 4; ++sI) {
        u32x2 d;
        d[0] = cvt_pk_bf16(sacc[tI][sI][0], sacc[tI][sI][1]);
        d[1] = cvt_pk_bf16(sacc[tI][sI][2], sacc[tI][sI][3]);
        *(u32x2*)(Pw + (tI * 16 + lr) * PSTR + sI * 16 + lg * 4) = d;
      }

    // PV: O[t][d] += P[t][s] * V[d][s]
#pragma unroll
    for (int tI = 0; tI < 2; ++tI) {
      const bf16x8 ap0 = *(const bf16x8*)(Pw + (tI * 16 + lr) * PSTR + lg * 8);
      const bf16x8 ap1 = *(const bf16x8*)(Pw + (tI * 16 + lr) * PSTR + 32 + lg * 8);
      __builtin_amdgcn_s_setprio(1);
#pragma unroll
      for (int dI = 0; dI < 4; ++dI) {
        const bf16x8 bv0 = *(const bf16x8*)(Vs + (dI * 16 + lr) * PSTR + lg * 8);
        const bf16x8 bv1 = *(const bf16x8*)(Vs + (dI * 16 + lr) * PSTR + 32 + lg * 8);
        oacc[tI][dI] = mfma_bf16(ap0, bv0, oacc[tI][dI]);
        oacc[tI][dI] = mfma_bf16(ap1, bv1, oacc[tI][dI]);
      }
      __builtin_amdgcn_s_setprio(0);
    }

    if (st < 15) {
      __syncthreads();
      *(u32x4*)(Ks + srow * PSTR + sseg * 8) = kr0;
      *(u32x4*)(Ks + (srow + 32) * PSTR + sseg * 8) = kr1;
      *(u32x4*)(Vs + srow * PSTR + sseg * 8) = vr0;
      *(u32x4*)(Vs + (srow + 32) * PSTR + sseg * 8) = vr1;
      __syncthreads();
    }
  }

  float inv[2][4];
#pragma unroll
  for (int tI = 0; tI < 2; ++tI) {
    float tot = lrun[tI];
    tot += __shfl_xor(tot, 16);
    tot += __shfl_xor(tot, 32);
#pragma unroll
    for (int r = 0; r < 4; ++r)
      inv[tI][r] = 1.f / __shfl(tot, (lane & 48) | (lg * 4 + r));
  }
#pragma unroll
  for (int tI = 0; tI < 2; ++tI)
#pragma unroll
    for (int dI = 0; dI < 4; ++dI)
#pragma unroll
      for (int r = 0; r < 4; ++r) {
        const int t = qt * 128 + w * 32 + tI * 16 + lg * 4 + r;
        attnT[((size_t)b * 1024 + t) * 512 + h * 64 + dI * 16 + lr] =
            f2bf(oacc[tI][dI][r] * inv[tI][r]);
      }
}

// ---------------- proj GEMM + bias + residual -> out (b, c, t) fp32 ----------------
// global_load_lds staging, double-buffered linear LDS [128][32], 1 sync/K-step.
__global__ __launch_bounds__(256) void k_proj(const ushort_t* __restrict__ attnT,
                                              const ushort_t* __restrict__ Wbf,
                                              const float* __restrict__ bias,
                                              const float* __restrict__ xres,
                                              float* __restrict__ outp) {
  const int mi = blockIdx.x, ni = blockIdx.y, b = blockIdx.z;
  const int tid = threadIdx.x, lane = tid & 63, w = tid >> 6;
  const int wm = w >> 1, wn = w & 1;
  const int lr = lane & 15, lg = lane >> 4;

  __shared__ __align__(16) ushort_t As[2][4096];
  __shared__ __align__(16) ushort_t Bs[2][4096];
  __shared__ __align__(16) float tbuf[32 * 132];

  const ushort_t* Ap = attnT + (size_t)b * 1024 * 512 + (size_t)mi * 128 * 512;
  const ushort_t* Bp = Wbf + (size_t)ni * 128 * 512;

  const int r0 = tid >> 2, sg = tid & 3;
  const int wbase0 = w * 512;
  const int wbase1 = 2048 + w * 512;

  gload16(Ap + (size_t)r0 * 512 + sg * 8,        &As[0][wbase0]);
  gload16(Ap + (size_t)(r0 + 64) * 512 + sg * 8, &As[0][wbase1]);
  gload16(Bp + (size_t)r0 * 512 + sg * 8,        &Bs[0][wbase0]);
  gload16(Bp + (size_t)(r0 + 64) * 512 + sg * 8, &Bs[0][wbase1]);
  __syncthreads();

  f32x4 acc[4][4] = {};

  for (int kt = 0; kt < 16; ++kt) {
    const int cur = kt & 1;
    if (kt < 15) {
      const int k0n = (kt + 1) * 32;
      gload16(Ap + (size_t)r0 * 512 + k0n + sg * 8,        &As[cur ^ 1][wbase0]);
      gload16(Ap + (size_t)(r0 + 64) * 512 + k0n + sg * 8, &As[cur ^ 1][wbase1]);
      gload16(Bp + (size_t)r0 * 512 + k0n + sg * 8,        &Bs[cur ^ 1][wbase0]);
      gload16(Bp + (size_t)(r0 + 64) * 512 + k0n + sg * 8, &Bs[cur ^ 1][wbase1]);
    }
    bf16x8 af[4], bfv[4];
#pragma unroll
    for (int i = 0; i < 4; ++i)
      af[i] = *(const bf16x8*)(&As[cur][(wm * 64 + i * 16 + lr) * 32 + lg * 8]);
#pragma unroll
    for (int j = 0; j < 4; ++j)
      bfv[j] = *(const bf16x8*)(&Bs[cur][(wn * 64 + j * 16 + lr) * 32 + lg * 8]);
    __builtin_amdgcn_s_setprio(1);
#pragma unroll
    for (int i = 0; i < 4; ++i)
#pragma unroll
      for (int j = 0; j < 4; ++j)
        acc[i][j] = mfma_bf16(af[i], bfv[j], acc[i][j]);
    __builtin_amdgcn_s_setprio(0);
    __syncthreads();
  }

  float biasv[4];
#pragma unroll
  for (int j = 0; j < 4; ++j) biasv[j] = bias[ni * 128 + wn * 64 + j * 16 + lr];

  // transpose (t,o)->(o,t) through LDS in 32-col chunks, add residual, fp32 out
#pragma unroll
  for (int c = 0; c < 4; ++c) {
    if (wn == (c >> 1)) {
#pragma unroll
      for (int jj = 0; jj < 2; ++jj) {
        const int j = (c & 1) * 2 + jj;
#pragma unroll
        for (int i = 0; i < 4; ++i)
#pragma unroll
          for (int r = 0; r < 4; ++r) {
            const int m = wm * 64 + i * 16 + lg * 4 + r;
            const int nl = jj * 16 + lr;
            tbuf[nl * 132 + m] = acc[i][j][r] + biasv[j];
          }
      }
    }
    __syncthreads();
    for (int u = tid; u < 1024; u += 256) {
      const int nl = u >> 5, sgx = u & 31;
      const int o = ni * 128 + c * 32 + nl;
      const size_t idx = ((size_t)b * 512 + o) * 1024 + mi * 128 + sgx * 4;
      const f32x4 t = *(const f32x4*)(tbuf + nl * 132 + sgx * 4);
      const f32x4 xr = *(const f32x4*)(xres + idx);
      f32x4 ov = t + xr;
      *(f32x4*)(outp + idx) = ov;
    }
    __syncthreads();
  }
}

extern "C" void kernel_launch(void* const* d_in, const int* in_sizes, int n_in,
                              void* d_out, int out_size, void* d_ws, size_t ws_size,
                              hipStream_t stream) {
  (void)in_sizes; (void)n_in; (void)out_size; (void)ws_size;
  const float* x      = (const float*)d_in[0];
  const float* gsc    = (const float*)d_in[1];
  const float* gbi    = (const float*)d_in[2];
  const float* qkv_w  = (const float*)d_in[3];
  const float* qkv_b  = (const float*)d_in[4];
  const float* proj_w = (const float*)d_in[5];
  const float* proj_b = (const float*)d_in[6];
  float* out = (float*)d_out;

  char* ws = (char*)d_ws;
  ushort_t* xnT   = (ushort_t*)(ws);               // (16,1024,512) bf16  16 MiB
  ushort_t* qkT   = (ushort_t*)(ws + 16777216);    // (16,1024,1024) bf16 32 MiB
  ushort_t* vbuf  = (ushort_t*)(ws + 50331648);    // (16,512,1024) bf16  16 MiB
  ushort_t* attnT = (ushort_t*)(ws + 67108864);    // (16,1024,512) bf16  16 MiB
  ushort_t* qwbf  = (ushort_t*)(ws + 83886080);    // (1536,512) bf16
  ushort_t* pwbf  = (ushort_t*)(ws + 85458944);    // (512,512) bf16

  k_convert<<<768, 256, 0, stream>>>(qkv_w, qwbf, 1536 * 512);
  k_convert<<<256, 256, 0, stream>>>(proj_w, pwbf, 512 * 512);
  k_gn<<<dim3(32, 16), 256, 0, stream>>>(x, gsc, gbi, xnT);
  k_qkv<<<dim3(8, 12, 16), 256, 0, stream>>>(xnT, qwbf, qkv_b, qkT, vbuf);
  k_attn<<<1024, 256, 0, stream>>>(qkT, vbuf, attnT);
  k_proj<<<dim3(8, 4, 16), 256, 0, stream>>>(attnT, pwbf, proj_b, x, out);
}